// Round 1
// baseline (59.327 us; speedup 1.0000x reference)
//
#include <hip/hip_runtime.h>

// Problem geometry (fixed by the reference):
//   prev_x: [128, 256, 28, 28] f32  -> PREV_CHW = 200704 per batch
//   curr_x: [128, 512, 14, 14] f32  -> CURR_CHW = 100352 per batch
//   out:    [256, 28, 28] f32       -> 200704 elements
// out[chw] = sum_b (prev_x[b,chw] > 0) * popcount_pos(curr_x[b])
// All values are integers < 2^24 -> exact in fp32 regardless of order.

constexpr int NB       = 128;
constexpr int PREV_CHW = 256 * 28 * 28;   // 200704
constexpr int CURR_CHW = 512 * 14 * 14;   // 100352
constexpr int PREV_V4  = PREV_CHW / 4;    // 50176
constexpr int CURR_V4  = CURR_CHW / 4;    // 25088
constexpr int GROUPS   = 8;               // batch-split for kernel 2
constexpr int B_PER_G  = NB / GROUPS;     // 16

// Kernel 1: per-batch positive count of curr_x. grid = (128 batches, 4 quarters).
__global__ void __launch_bounds__(256)
count_pos_kernel(const float* __restrict__ curr, float* __restrict__ sums) {
    const int b = blockIdx.x;
    const int q = blockIdx.y;
    constexpr int QUARTER = CURR_V4 / 4;  // 6272 float4 per quarter
    const float4* p = reinterpret_cast<const float4*>(curr)
                      + (size_t)b * CURR_V4 + (size_t)q * QUARTER;
    int cnt = 0;
    for (int i = threadIdx.x; i < QUARTER; i += 256) {
        float4 v = p[i];
        cnt += (v.x > 0.0f);
        cnt += (v.y > 0.0f);
        cnt += (v.z > 0.0f);
        cnt += (v.w > 0.0f);
    }
    // wave64 reduction
    #pragma unroll
    for (int off = 32; off > 0; off >>= 1)
        cnt += __shfl_down(cnt, off, 64);
    if ((threadIdx.x & 63) == 0)
        atomicAdd(&sums[b], (float)cnt);  // integer-valued -> exact
}

// Kernel 2: out += (prev>0) * sums[b], batch dim split into GROUPS for occupancy.
// grid = (196, GROUPS) x 256 threads; one float4 of output per thread.
__global__ void __launch_bounds__(256)
corr_kernel(const float* __restrict__ prev, const float* __restrict__ sums,
            float* __restrict__ out) {
    const int i  = blockIdx.x * 256 + threadIdx.x;  // float4 index, 0..50175
    const int b0 = blockIdx.y * B_PER_G;
    const float4* pv = reinterpret_cast<const float4*>(prev) + i;

    float4 acc = make_float4(0.0f, 0.0f, 0.0f, 0.0f);
    #pragma unroll 4
    for (int bb = 0; bb < B_PER_G; ++bb) {
        const int b = b0 + bb;
        const float s = sums[b];                     // uniform, cache-resident
        const float4 v = pv[(size_t)b * PREV_V4];    // fully coalesced 16B/lane
        acc.x += (v.x > 0.0f) ? s : 0.0f;
        acc.y += (v.y > 0.0f) ? s : 0.0f;
        acc.z += (v.z > 0.0f) ? s : 0.0f;
        acc.w += (v.w > 0.0f) ? s : 0.0f;
    }
    float* o = out + 4 * (size_t)i;
    atomicAdd(o + 0, acc.x);   // 8 adders per address; integer-valued -> exact
    atomicAdd(o + 1, acc.y);
    atomicAdd(o + 2, acc.z);
    atomicAdd(o + 3, acc.w);
}

extern "C" void kernel_launch(void* const* d_in, const int* in_sizes, int n_in,
                              void* d_out, int out_size, void* d_ws, size_t ws_size,
                              hipStream_t stream) {
    const float* prev = (const float*)d_in[0];
    const float* curr = (const float*)d_in[1];
    float* out  = (float*)d_out;
    float* sums = (float*)d_ws;   // 128 floats of scratch

    hipMemsetAsync(sums, 0, NB * sizeof(float), stream);
    hipMemsetAsync(out, 0, (size_t)out_size * sizeof(float), stream);

    count_pos_kernel<<<dim3(NB, 4), 256, 0, stream>>>(curr, sums);
    corr_kernel<<<dim3(PREV_V4 / 256, GROUPS), 256, 0, stream>>>(prev, sums, out);
}

// Round 2
// 30.756 us; speedup vs baseline: 1.9290x; 1.9290x over previous
//
#include <hip/hip_runtime.h>

// Problem geometry (fixed by the reference):
//   prev_x: [128, 256, 28, 28] f32  -> PREV_CHW = 200704 per batch
//   curr_x: [128, 512, 14, 14] f32  -> CURR_CHW = 100352 per batch
//   out:    [256, 28, 28] f32       -> 200704 elements
// out[chw] = sum_b (prev_x[b,chw] > 0) * popcount_pos(curr_x[b])
// All values are integers <= 128*100352 < 2^24 -> exact in fp32 in any order.
//
// R2 design notes:
//  - NO hipMemsetAsync in the graph (R1 rocprof: fillBufferAligned dispatches
//    dominated; the 784 KB out-clear ran at 14 GB/s).
//  - NO atomics: kernel 1 direct-stores partials, kernel 2 direct-stores out.

constexpr int NB       = 128;
constexpr int PREV_CHW = 256 * 28 * 28;   // 200704
constexpr int CURR_CHW = 512 * 14 * 14;   // 100352
constexpr int PREV_V4  = PREV_CHW / 4;    // 50176
constexpr int CURR_V4  = CURR_CHW / 4;    // 25088
constexpr int QUARTER  = CURR_V4 / 4;     // 6272 float4 per (batch, quarter)

// Kernel 1: partial positive-count of curr_x. grid = (128 batches, 4 quarters),
// 512 blocks total -> all 256 CUs busy, no init, no atomics.
__global__ void __launch_bounds__(256)
count_pos_kernel(const float* __restrict__ curr, float* __restrict__ partial) {
    const int b = blockIdx.x;
    const int q = blockIdx.y;
    const float4* p = reinterpret_cast<const float4*>(curr)
                      + (size_t)b * CURR_V4 + (size_t)q * QUARTER;
    int cnt = 0;
    for (int i = threadIdx.x; i < QUARTER; i += 256) {
        float4 v = p[i];
        cnt += (v.x > 0.0f);
        cnt += (v.y > 0.0f);
        cnt += (v.z > 0.0f);
        cnt += (v.w > 0.0f);
    }
    // wave64 shuffle reduction, then 4-wave LDS fold
    #pragma unroll
    for (int off = 32; off > 0; off >>= 1)
        cnt += __shfl_down(cnt, off, 64);
    __shared__ int wsum[4];
    if ((threadIdx.x & 63) == 0)
        wsum[threadIdx.x >> 6] = cnt;
    __syncthreads();
    if (threadIdx.x == 0)
        partial[q * NB + b] = (float)(wsum[0] + wsum[1] + wsum[2] + wsum[3]);
}

// Kernel 2: out[chw] = sum_b (prev>0) * sums[b]. One float4 of output per
// thread; each thread walks all 128 batches -> single direct store, no init.
// grid = 392 blocks x 128 threads (= 50176 float4, exact cover).
__global__ void __launch_bounds__(128)
corr_kernel(const float* __restrict__ prev, const float* __restrict__ partial,
            float* __restrict__ out) {
    __shared__ float s_sum[NB];
    const int t = threadIdx.x;
    // fold the 4 quarter-partials per batch (t indexes batch, 128 threads = NB)
    s_sum[t] = partial[t] + partial[NB + t] + partial[2 * NB + t] + partial[3 * NB + t];
    __syncthreads();

    const int i = blockIdx.x * 128 + t;          // float4 index, 0..50175
    const float4* pv = reinterpret_cast<const float4*>(prev) + i;

    float4 acc = make_float4(0.0f, 0.0f, 0.0f, 0.0f);
    #pragma unroll 16
    for (int b = 0; b < NB; ++b) {
        const float4 v = pv[(size_t)b * PREV_V4];  // coalesced 16 B/lane
        const float s = s_sum[b];                  // wave-uniform LDS broadcast
        acc.x += (v.x > 0.0f) ? s : 0.0f;
        acc.y += (v.y > 0.0f) ? s : 0.0f;
        acc.z += (v.z > 0.0f) ? s : 0.0f;
        acc.w += (v.w > 0.0f) ? s : 0.0f;
    }
    reinterpret_cast<float4*>(out)[i] = acc;       // single direct store
}

extern "C" void kernel_launch(void* const* d_in, const int* in_sizes, int n_in,
                              void* d_out, int out_size, void* d_ws, size_t ws_size,
                              hipStream_t stream) {
    const float* prev = (const float*)d_in[0];
    const float* curr = (const float*)d_in[1];
    float* out     = (float*)d_out;
    float* partial = (float*)d_ws;   // 512 floats of scratch, written before read

    count_pos_kernel<<<dim3(NB, 4), 256, 0, stream>>>(curr, partial);
    corr_kernel<<<PREV_V4 / 128, 128, 0, stream>>>(prev, partial, out);
}